// Round 7
// baseline (307.038 us; speedup 1.0000x reference)
//
#include <hip/hip_runtime.h>

// Problem constants (fixed by reference setup_inputs).
#define N 32
#define T 64
#define C 256
#define L 64
#define CHUNKS 32                  // blocks per n; each block owns 2 consecutive t-rows
#define GRID_BLOCKS (CHUNKS * N)   // 1024 blocks; launch_bounds(256,4) -> all co-resident
#define PARTIAL_ELEMS (CHUNKS * N * L)   // 65536 floats = 256 KiB
#define BAR_STRIDE 32              // 32 uints = 128 B between per-n counters

// Fused kernel with PER-N grid barrier (R5 post-mortem: global 1024-spinner
// barrier on one line collapsed; 32 spinners/line + 0.85us poll period is benign).
// Phase 1: partial[chunk][n][l] = sum_c over 2 t-rows of q[n,t,c,l]*k[t,n,c];
//          row t0 retained in registers/AGPRs across the barrier.
// Barrier: per-n counter -> only the 32 blocks sharing n synchronize.
// Phase 2: per-block softmax over its n's 32 partials (8 KiB, L2-hot), then
//          out[t0] from retained regs (zero q traffic), out[t1] re-streamed (L3-hot).
__global__ __launch_bounds__(256, 4) void fused_kernel(
    const float* __restrict__ q, const float* __restrict__ k,
    float* __restrict__ partial, unsigned int* __restrict__ bar,
    float* __restrict__ out) {
  const int chunk = blockIdx.x;   // 0..31
  const int n     = blockIdx.y;   // 0..31
  const int t0    = chunk * 2;
  const int tid   = threadIdx.x;
  const int lane  = tid & 63;
  const int wave  = tid >> 6;       // 0..3
  const int sub   = lane >> 4;      // 0..3
  const int lq    = lane & 15;      // l-group: l = 4*lq..4*lq+3
  const int g     = wave * 4 + sub; // quarter-wave id 0..15 -> c = g, g+16, ...

  __shared__ float ks[2 * C];      // k rows t0,t0+1 (2 KiB)
  __shared__ float sdata[4 * L];   // cross-wave reduce (1 KiB), reused in phase 2
  __shared__ float probs[L];

  ks[tid]     = k[t0 * (N * C) + n * C + tid];
  ks[tid + C] = k[(t0 + 1) * (N * C) + n * C + tid];
  __syncthreads();

  const float* q0 = q + ((size_t)n * T + t0) * (C * L);
  const float* q1 = q0 + (size_t)(C * L);

  // ---- Phase 1a: row t0, retained (64 VGPR/AGPR payload) ----
  float4 hold[16];
  #pragma unroll
  for (int j = 0; j < 16; ++j) {
    const int c = g + j * 16;
    hold[j] = *reinterpret_cast<const float4*>(q0 + (size_t)c * L + lq * 4);
  }
  float4 acc = make_float4(0.f, 0.f, 0.f, 0.f);
  #pragma unroll
  for (int j = 0; j < 16; ++j) {
    const float kv = ks[g + j * 16];
    acc.x = fmaf(hold[j].x, kv, acc.x);
    acc.y = fmaf(hold[j].y, kv, acc.y);
    acc.z = fmaf(hold[j].z, kv, acc.z);
    acc.w = fmaf(hold[j].w, kv, acc.w);
  }
  // ---- Phase 1b: row t1, streamed ----
  #pragma unroll
  for (int j = 0; j < 16; ++j) {
    const int c = g + j * 16;
    const float4 qv = *reinterpret_cast<const float4*>(q1 + (size_t)c * L + lq * 4);
    const float kv = ks[C + c];
    acc.x = fmaf(qv.x, kv, acc.x);
    acc.y = fmaf(qv.y, kv, acc.y);
    acc.z = fmaf(qv.z, kv, acc.z);
    acc.w = fmaf(qv.w, kv, acc.w);
  }

  // Quarter-wave accumulators hold same l-groups, different c: sum across subs.
  acc.x += __shfl_xor(acc.x, 16); acc.y += __shfl_xor(acc.y, 16);
  acc.z += __shfl_xor(acc.z, 16); acc.w += __shfl_xor(acc.w, 16);
  acc.x += __shfl_xor(acc.x, 32); acc.y += __shfl_xor(acc.y, 32);
  acc.z += __shfl_xor(acc.z, 32); acc.w += __shfl_xor(acc.w, 32);

  if (lane < 16) {
    sdata[wave * L + lq * 4 + 0] = acc.x;
    sdata[wave * L + lq * 4 + 1] = acc.y;
    sdata[wave * L + lq * 4 + 2] = acc.z;
    sdata[wave * L + lq * 4 + 3] = acc.w;
  }
  __syncthreads();
  if (tid < L) {
    const float s = sdata[tid] + sdata[L + tid] + sdata[2 * L + tid] + sdata[3 * L + tid];
    partial[(size_t)chunk * (N * L) + n * L + tid] = s;
  }
  __syncthreads();   // partial row written before tid0's release fence

  // ---- Per-n barrier: 32 blocks, own cache line, gentle poll ----
  if (tid == 0) {
    unsigned int* my_bar = bar + n * BAR_STRIDE;
    __threadfence();                       // release this block's partial row
    atomicAdd(my_bar, 1u);                 // device scope by default
    while (__hip_atomic_load(my_bar, __ATOMIC_ACQUIRE, __HIP_MEMORY_SCOPE_AGENT)
           < (unsigned)CHUNKS) {
      __builtin_amdgcn_s_sleep(32);        // ~0.85 us between polls
    }
    __threadfence();
  }
  __syncthreads();

  // ---- Phase 2: softmax over l (redundant per block; 8 KiB L2-hot) ----
  {
    float s = 0.f;   // wave w sums partial chunks [8w, 8w+8), lane = l
    #pragma unroll
    for (int b = wave * 8; b < wave * 8 + 8; ++b)
      s += partial[(size_t)b * (N * L) + n * L + lane];
    sdata[wave * L + lane] = s;
  }
  __syncthreads();
  if (tid < L) {   // exactly wave 0
    float s = sdata[tid] + sdata[L + tid] + sdata[2 * L + tid] + sdata[3 * L + tid];
    float m = s;
    #pragma unroll
    for (int off = 32; off > 0; off >>= 1) m = fmaxf(m, __shfl_xor(m, off));
    const float e = __expf(s - m);
    float sum = e;
    #pragma unroll
    for (int off = 32; off > 0; off >>= 1) sum += __shfl_xor(sum, off);
    probs[tid] = e / sum;
  }
  __syncthreads();

  const float4 pv = *reinterpret_cast<const float4*>(&probs[lq * 4]);

  // ---- Phase 2a: row t0 from retained registers (zero q traffic) ----
  #pragma unroll
  for (int j = 0; j < 16; ++j) {
    float d = hold[j].x * pv.x + hold[j].y * pv.y + hold[j].z * pv.z + hold[j].w * pv.w;
    d += __shfl_xor(d, 1);
    d += __shfl_xor(d, 2);
    d += __shfl_xor(d, 4);
    d += __shfl_xor(d, 8);
    if (lq == 0)
      __builtin_nontemporal_store(d, &out[t0 * (N * C) + n * C + (g + j * 16)]);
  }
  // ---- Phase 2b: row t1 re-streamed (L3-hot from phase 1) ----
  #pragma unroll
  for (int j = 0; j < 16; ++j) {
    const int c = g + j * 16;
    const float4 qv = *reinterpret_cast<const float4*>(q1 + (size_t)c * L + lq * 4);
    float d = qv.x * pv.x + qv.y * pv.y + qv.z * pv.z + qv.w * pv.w;
    d += __shfl_xor(d, 1);
    d += __shfl_xor(d, 2);
    d += __shfl_xor(d, 4);
    d += __shfl_xor(d, 8);
    if (lq == 0)
      __builtin_nontemporal_store(d, &out[(t0 + 1) * (N * C) + n * C + c]);
  }
}

extern "C" void kernel_launch(void* const* d_in, const int* in_sizes, int n_in,
                              void* d_out, int out_size, void* d_ws, size_t ws_size,
                              hipStream_t stream) {
  const float* q = (const float*)d_in[0];   // query: (32,64,256,64) fp32
  const float* k = (const float*)d_in[1];   // key:   (64,32,256)    fp32
  float* out = (float*)d_out;               // out:   (64,32,256)    fp32
  float* partial = (float*)d_ws;            // [32][32][64] fp32 = 256 KiB
  unsigned int* bar = (unsigned int*)((char*)d_ws + (size_t)PARTIAL_ELEMS * 4);

  // Zero the 32 per-n barrier counters (ws is poisoned 0xAA before every launch).
  hipMemsetAsync((void*)bar, 0, N * BAR_STRIDE * sizeof(unsigned int), stream);

  dim3 grid(CHUNKS, N);                     // 1024 blocks x 256 threads, 4/CU
  fused_kernel<<<grid, 256, 0, stream>>>(q, k, partial, bar, out);
}